// Round 16
// baseline (1501.749 us; speedup 1.0000x reference)
//
#include <hip/hip_runtime.h>
#include <hip/hip_bf16.h>
#include <math.h>

#define T_LEN 4096
#define EMBD 1024
#define DH 128
#define NHASH 8
#define NHEADS 8

typedef __attribute__((ext_vector_type(8))) short short8;
typedef __attribute__((ext_vector_type(16))) float f32x16;

// LDS swizzle: row-major [r][128] bf16, 16B-block XOR by (row&7) — G4 fix.
__device__ __forceinline__ int swz(int row, int col) {
    return (row << 7) + (col ^ ((row & 7) << 3));
}
__device__ __forceinline__ unsigned cvtpk(float lo, float hi) {
    unsigned r;
    asm("v_cvt_pk_bf16_f32 %0, %1, %2" : "=v"(r) : "v"(lo), "v"(hi));
    return r;
}
__device__ __forceinline__ float bfu_lo(unsigned u) {
    union { unsigned x; float f; } c; c.x = u << 16; return c.f;
}
__device__ __forceinline__ float bfu_hi(unsigned u) {
    union { unsigned x; float f; } c; c.x = u & 0xffff0000u; return c.f;
}
__device__ __forceinline__ float bfus2f(unsigned short s) {
    union { unsigned x; float f; } c; c.x = ((unsigned)s) << 16; return c.f;
}

// ------------------------------------------------------------------
// K1a: qk = x @ w_qk in f64. 4 rows/block, 512 threads =
// (256 col-groups × 2 e-halves). Each thread: 4 rows × 4 cols over its
// 512-e half (acc = 32 VGPR -> high occupancy). Halves combined in LDS
// (f64 add; ~1e-16 deviation, 8 orders under proven-safe hash band).
// Emits qk32+qkr (2^-33), qkh/qkl (hi/lo bf16 of f32 qk), rsn.
// ------------------------------------------------------------------
__global__ __launch_bounds__(512) void k_qk_gemm(
    const float* __restrict__ x, const float* __restrict__ wqk,
    float* __restrict__ qk32, __hip_bfloat16* __restrict__ qkr,
    __hip_bfloat16* __restrict__ qkh, __hip_bfloat16* __restrict__ qkl,
    float* __restrict__ rsn)
{
    __shared__ float xs[4][EMBD];      // 16 KB; aliased as f64 ps[] post-loop
    const int row0 = blockIdx.x * 4;
    const int tid = threadIdx.x;       // 0..511
    const int cg = tid & 255;          // col group: cols 4cg..4cg+3
    const int gh = tid >> 8;           // e-half: [0,512) or [512,1024)

    for (int u = tid; u < 4 * 256; u += 512) {
        int rr = u >> 8, q = u & 255;
        reinterpret_cast<float4*>(xs[rr])[q] =
            reinterpret_cast<const float4*>(x + (size_t)(row0 + rr) * EMBD)[q];
    }
    __syncthreads();

    double a[4][4] = {};
    {
        const float* wp = wqk + 4 * cg;
        const int e0 = gh << 9;
        for (int e = e0; e < e0 + 512; ++e) {
            float4 w4 = *reinterpret_cast<const float4*>(wp + (size_t)e * EMBD);
            double w0 = (double)w4.x, w1 = (double)w4.y;
            double w2 = (double)w4.z, w3 = (double)w4.w;
            #pragma unroll
            for (int rr = 0; rr < 4; ++rr) {
                double xe = (double)xs[rr][e];
                a[rr][0] = fma(xe, w0, a[rr][0]);
                a[rr][1] = fma(xe, w1, a[rr][1]);
                a[rr][2] = fma(xe, w2, a[rr][2]);
                a[rr][3] = fma(xe, w3, a[rr][3]);
            }
        }
    }
    __syncthreads();   // xs reads done; alias region as f64 exchange
    double* ps = reinterpret_cast<double*>(&xs[0][0]);   // [cc*2+rr][cg]
    #pragma unroll
    for (int half = 0; half < 2; ++half) {
        if (gh == 1) {
            #pragma unroll
            for (int cc = 0; cc < 4; ++cc)
                #pragma unroll
                for (int rr = 0; rr < 2; ++rr)
                    ps[(cc * 2 + rr) * 256 + cg] = a[half * 2 + rr][cc];
        }
        __syncthreads();
        if (gh == 0) {
            #pragma unroll
            for (int cc = 0; cc < 4; ++cc)
                #pragma unroll
                for (int rr = 0; rr < 2; ++rr)
                    a[half * 2 + rr][cc] += ps[(cc * 2 + rr) * 256 + cg];
        }
        __syncthreads();
    }

    if (gh == 0) {     // epilogue: threads 0..255 = full waves 0-3
        const int j = 4 * cg;
        const int h = j >> 7, d = j & 127;
        #pragma unroll
        for (int rr = 0; rr < 4; ++rr) {
            float f0 = (float)a[rr][0], f1 = (float)a[rr][1];
            float f2 = (float)a[rr][2], f3 = (float)a[rr][3];
            float ss = f0*f0 + f1*f1 + f2*f2 + f3*f3;
            #pragma unroll
            for (int m = 1; m < 32; m <<= 1) ss += __shfl_xor(ss, m);
            float rs = 1.0f / sqrtf(fmaxf(ss, 1e-12f));

            int row = row0 + rr;
            int b = row >> 12, t = row & 4095;
            size_t base = ((size_t)(b * NHEADS + h) * T_LEN + t) * DH + d;

            float4 q4; q4.x = f0; q4.y = f1; q4.z = f2; q4.w = f3;
            *reinterpret_cast<float4*>(qk32 + base) = q4;
            float r0 = (float)(a[rr][0] - (double)f0);
            float r1 = (float)(a[rr][1] - (double)f1);
            float r2 = (float)(a[rr][2] - (double)f2);
            float r3 = (float)(a[rr][3] - (double)f3);
            *reinterpret_cast<uint2*>(qkr + base) = make_uint2(cvtpk(r0, r1), cvtpk(r2, r3));

            unsigned h01 = cvtpk(f0, f1), h23 = cvtpk(f2, f3);
            float l0 = f0 - bfu_lo(h01), l1 = f1 - bfu_hi(h01);
            float l2 = f2 - bfu_lo(h23), l3 = f3 - bfu_hi(h23);
            *reinterpret_cast<uint2*>(qkh + base) = make_uint2(h01, h23);
            *reinterpret_cast<uint2*>(qkl + base) = make_uint2(cvtpk(l0, l1), cvtpk(l2, l3));
            if ((cg & 31) == 0)
                rsn[(size_t)(b * NHEADS + h) * T_LEN + t] = rs;
        }
    }
}

// ------------------------------------------------------------------
// K1b: LSH hash — unchanged (proven).
// ------------------------------------------------------------------
__global__ __launch_bounds__(256) void k_hash(
    const float* __restrict__ qk32, const __hip_bfloat16* __restrict__ qkr,
    const float* __restrict__ rot, unsigned* __restrict__ bucketArr)
{
    __shared__ double qs[8][EMBD];     // 64 KB
    const int tok0 = blockIdx.x * 8;
    const int tid = threadIdx.x;
    const int j = 4 * tid;
    const int h = j >> 7, d = j & 127;

    #pragma unroll
    for (int tk = 0; tk < 8; ++tk) {
        int row = tok0 + tk;
        int b = row >> 12, t = row & 4095;
        size_t base = ((size_t)(b * NHEADS + h) * T_LEN + t) * DH + d;
        float4 f4 = *reinterpret_cast<const float4*>(qk32 + base);
        ushort4 r4 = *reinterpret_cast<const ushort4*>(qkr + base);
        qs[tk][j + 0] = (double)f4.x + (double)bfus2f(r4.x);
        qs[tk][j + 1] = (double)f4.y + (double)bfus2f(r4.y);
        qs[tk][j + 2] = (double)f4.z + (double)bfus2f(r4.z);
        qs[tk][j + 3] = (double)f4.w + (double)bfus2f(r4.w);
    }
    __syncthreads();

    const int r = tid >> 5, i = tid & 31;
    const float* rp = rot + r * 32 + i;
    for (int hh = 0; hh < NHEADS; ++hh) {
        double acc[8] = {};
        for (int f = 0; f < DH; ++f) {
            double rv = (double)rp[(size_t)f * 256];
            #pragma unroll
            for (int tk = 0; tk < 8; ++tk)
                acc[tk] = fma(qs[tk][hh * DH + f], rv, acc[tk]);
        }
        #pragma unroll
        for (int tk = 0; tk < 8; ++tk) {
            double v; int idx;
            if (acc[tk] >= 0.0) { v = acc[tk]; idx = i; } else { v = -acc[tk]; idx = i + 32; }
            #pragma unroll
            for (int m = 1; m < 32; m <<= 1) {
                double ov = __shfl_xor(v, m);
                int oi = __shfl_xor(idx, m);
                if (ov > v || (ov == v && oi < idx)) { v = ov; idx = oi; }
            }
            if (i == 0) {
                int row = tok0 + tk;
                int b = row >> 12, t = row & 4095;
                bucketArr[((size_t)(b * NHEADS + hh) * NHASH + r) * T_LEN + t] = (unsigned)idx;
            }
        }
    }
}

// ------------------------------------------------------------------
// K2: v = x @ w_v, 8 rows/block -> v_bf16 (proven).
// ------------------------------------------------------------------
__global__ __launch_bounds__(256) void k_vproj(
    const float* __restrict__ x, const float* __restrict__ wv,
    __hip_bfloat16* __restrict__ vb)
{
    __shared__ float xs[8][EMBD];      // 32 KB
    const int row0 = blockIdx.x * 8;
    const int tid = threadIdx.x;
    #pragma unroll
    for (int rr = 0; rr < 8; ++rr)
        reinterpret_cast<float4*>(xs[rr])[tid] =
            reinterpret_cast<const float4*>(x + (size_t)(row0 + rr) * EMBD)[tid];
    __syncthreads();

    float acc[8][4] = {};
    const float* wp = wv + 4 * tid;
    for (int e = 0; e < EMBD; ++e) {
        float4 w4 = *reinterpret_cast<const float4*>(wp + (size_t)e * EMBD);
        #pragma unroll
        for (int rr = 0; rr < 8; ++rr) {
            float xe = xs[rr][e];
            acc[rr][0] = fmaf(xe, w4.x, acc[rr][0]);
            acc[rr][1] = fmaf(xe, w4.y, acc[rr][1]);
            acc[rr][2] = fmaf(xe, w4.z, acc[rr][2]);
            acc[rr][3] = fmaf(xe, w4.w, acc[rr][3]);
        }
    }
    int j = 4 * tid;
    int h = j >> 7, d = j & 127;
    #pragma unroll
    for (int rr = 0; rr < 8; ++rr) {
        int row = row0 + rr;
        int b = row >> 12, t = row & 4095;
        *reinterpret_cast<uint2*>(vb + ((size_t)(b * NHEADS + h) * T_LEN + t) * DH + d)
            = make_uint2(cvtpk(acc[rr][0], acc[rr][1]), cvtpk(acc[rr][2], acc[rr][3]));
    }
}

// ------------------------------------------------------------------
// K3: stable counting sort per (B, hash-round) — unchanged (proven).
// ------------------------------------------------------------------
__global__ __launch_bounds__(64) void k_sort(
    const unsigned* __restrict__ bucketArr, unsigned* __restrict__ st)
{
    __shared__ unsigned short bkt[T_LEN];
    __shared__ unsigned hist[64][64];
    __shared__ unsigned bstart[64];
    const int B = blockIdx.x >> 3, r = blockIdx.x & 7;
    const unsigned* src = bucketArr + ((size_t)B * NHASH + r) * T_LEN;
    const int tid = threadIdx.x;

    for (int k = tid; k < T_LEN; k += 64) bkt[k] = (unsigned short)src[k];
    for (int k = tid; k < 64 * 64; k += 64) (&hist[0][0])[k] = 0;
    __syncthreads();
    {
        const int base = tid * 64;
        for (int k = 0; k < 64; ++k) hist[tid][bkt[base + k]]++;
    }
    __syncthreads();
    {
        unsigned tot = 0;
        for (int c = 0; c < 64; ++c) tot += hist[c][tid];
        bstart[tid] = tot;
    }
    __syncthreads();
    if (tid == 0) {
        unsigned run = 0;
        for (int q = 0; q < 64; ++q) { unsigned c = bstart[q]; bstart[q] = run; run += c; }
    }
    __syncthreads();
    {
        unsigned run = bstart[tid];
        for (int c = 0; c < 64; ++c) { unsigned h = hist[c][tid]; hist[c][tid] = run; run += h; }
    }
    __syncthreads();
    {
        unsigned* dst = st + ((size_t)B * NHASH + r) * T_LEN;
        const int base = tid * 64;
        for (int k = 0; k < 64; ++k) {
            unsigned bb2 = bkt[base + k];
            unsigned p = hist[tid][bb2]++;
            dst[p] = (unsigned)(base + k);
        }
    }
}

// ------------------------------------------------------------------
// K4: per-bin attention, ONE PASS per hash round (online cross-round
// softmax) — unchanged (proven round 15).
// ------------------------------------------------------------------
__global__ __launch_bounds__(256, 2) void k_bin_pv(
    const __hip_bfloat16* __restrict__ qkh, const __hip_bfloat16* __restrict__ qkl,
    const __hip_bfloat16* __restrict__ vb, const float* __restrict__ rsn,
    const unsigned* __restrict__ st, float* __restrict__ Mbuf,
    float* __restrict__ Sbuf, float* __restrict__ attn, int rnd)
{
    __shared__ short Kh[128 * 128];        // K_hi -> P f32 [128][64] -> out scratch
    __shared__ short KV[128 * 128];        // V^T swizzled (staged upfront)
    __shared__ int ktok[128];
    __shared__ float rs_l[128];
    __shared__ float red4b[2][2][2][32];   // [it][jt2][h5][col]
    __shared__ float mrow[64];
    __shared__ float abrow[64][2];         // per-query (a, b) weights

    const int tid = threadIdx.x;
    const int c = blockIdx.x & 63;
    const int B = blockIdx.x >> 6;
    const unsigned* stp = st + ((size_t)B * NHASH + rnd) * T_LEN;

    if (tid < 128) {
        int cc = (tid < 64) ? c : (c == 0 ? 1 : c - 1);
        int tok = (int)stp[cc * 64 + (tid & 63)];
        ktok[tid] = tok;
        rs_l[tid] = rsn[(size_t)B * T_LEN + tok];
    }
    __syncthreads();

    for (int u = tid; u < 128 * 16; u += 256) {
        int row = u >> 4, blk = u & 15;
        *reinterpret_cast<int4*>(&Kh[swz(row, blk * 8)]) =
            *reinterpret_cast<const int4*>(qkh + ((size_t)B * T_LEN + ktok[row]) * DH + blk * 8);
    }
    // stage V^T (swizzled rows of V^T: row=d, col=j)
    {
        int j2 = tid >> 1, dbase = (tid & 1) * 64;
        const __hip_bfloat16* vrow = vb + ((size_t)B * T_LEN + ktok[j2]) * DH + dbase;
        #pragma unroll
        for (int mch = 0; mch < 8; ++mch) {
            short8 vv = *reinterpret_cast<const short8*>(vrow + mch * 8);
            #pragma unroll
            for (int e = 0; e < 8; ++e)
                KV[swz(dbase + mch * 8 + e, j2)] = vv[e];
        }
    }

    const int wave = tid >> 6, lane = tid & 63;
    const int it = wave & 1, jt2 = wave >> 1;
    const int h5 = lane >> 5;
    const int i_loc = it * 32 + (lane & 31);
    const int qtok_i = ktok[i_loc];
    short8 qfh[8], qfl[8];
    {
        size_t qoff = ((size_t)B * T_LEN + qtok_i) * DH + (h5 << 3);
        #pragma unroll
        for (int kt = 0; kt < 8; ++kt) {
            qfh[kt] = *reinterpret_cast<const short8*>(qkh + qoff + kt * 16);
            qfl[kt] = *reinterpret_cast<const short8*>(qkl + qoff + kt * 16);
        }
    }
    __syncthreads();

    const float scale = 0.08838834764831845f;
    float p2[2][16];   // raw masked dots, then P
    #pragma unroll
    for (int jj = 0; jj < 2; ++jj) {
        int jt = jt2 * 2 + jj;
        f32x16 acc = {};
        #pragma unroll
        for (int kt = 0; kt < 8; ++kt) {        // FULL K, 2-term split S
            int so = swz(jt * 32 + (lane & 31), kt * 16 + (h5 << 3));
            short8 afh = *reinterpret_cast<const short8*>(&Kh[so]);
            acc = __builtin_amdgcn_mfma_f32_32x32x16_bf16(afh, qfh[kt], acc, 0, 0, 0);
            acc = __builtin_amdgcn_mfma_f32_32x32x16_bf16(afh, qfl[kt], acc, 0, 0, 0);
        }
        #pragma unroll
        for (int r2 = 0; r2 < 16; ++r2) {
            int jl = (r2 & 3) + ((r2 >> 2) << 3) + (h5 << 2);
            int jf = jt * 32 + jl;
            float s = acc[r2] * (scale * rs_l[jf]);
            p2[jj][r2] = (ktok[jf] == qtok_i) ? -1e5f : s;
        }
    }

    // ---- per-query max over 128 keys ----
    float mloc = p2[0][0];
    #pragma unroll
    for (int jj = 0; jj < 2; ++jj)
        #pragma unroll
        for (int r2 = 0; r2 < 16; ++r2) mloc = fmaxf(mloc, p2[jj][r2]);
    red4b[it][jt2][h5][lane & 31] = mloc;
    __syncthreads();
    if (tid < 64) {
        int it2 = tid >> 5, i = tid & 31;
        mrow[tid] = fmaxf(fmaxf(red4b[it2][0][0][i], red4b[it2][0][1][i]),
                          fmaxf(red4b[it2][1][0][i], red4b[it2][1][1][i]));
    }
    __syncthreads();

    // ---- P = exp(S - m); per-query sum ----
    const float mi = mrow[i_loc];
    float sloc = 0.f;
    #pragma unroll
    for (int jj = 0; jj < 2; ++jj)
        #pragma unroll
        for (int r2 = 0; r2 < 16; ++r2) {
            float p = __expf(p2[jj][r2] - mi);
            p2[jj][r2] = p;
            sloc += p;
        }
    __syncthreads();           // red4b max-phase reads done
    red4b[it][jt2][h5][lane & 31] = sloc;
    __syncthreads();
    if (tid < 64) {
        int it2 = tid >> 5, i = tid & 31;
        float sr = red4b[it2][0][0][i] + red4b[it2][0][1][i] +
                   red4b[it2][1][0][i] + red4b[it2][1][1][i];
        float m = mrow[tid];
        size_t gi = (size_t)B * T_LEN + ktok[tid];
        float aw, bw;
        if (rnd == 0) {
            Mbuf[gi] = m; Sbuf[gi] = sr;
            aw = 0.f; bw = 1.f;
        } else {
            float Mold = Mbuf[gi];
            float Mnew = fmaxf(Mold, m);
            aw = __expf(Mold - Mnew);
            bw = __expf(m - Mnew);
            Sbuf[gi] = Sbuf[gi] * aw + sr * bw;
            Mbuf[gi] = Mnew;
        }
        abrow[tid][0] = aw; abrow[tid][1] = bw;
    }

    // write P f32 into Kh region: Pl[j][i]
    float* Pl = reinterpret_cast<float*>(Kh);
    #pragma unroll
    for (int jj = 0; jj < 2; ++jj) {
        int jt = jt2 * 2 + jj;
        #pragma unroll
        for (int r2 = 0; r2 < 16; ++r2) {
            int jl = (r2 & 3) + ((r2 >> 2) << 3) + (h5 << 2);
            Pl[(jt * 32 + jl) * 64 + i_loc] = p2[jj][r2];
        }
    }
    __syncthreads();

    // MFMA PV: B-frags packed from Pl (single bf16 term); A = V^T tiles.
    f32x16 oacc[4] = {};
    #pragma unroll
    for (int jj = 0; jj < 2; ++jj) {
        int jt = jt2 * 2 + jj;
        #pragma unroll
        for (int ks = 0; ks < 2; ++ks) {
            int jbase = jt * 32 + ks * 16 + h5 * 8;
            union Pack { unsigned u[4]; short8 v; } ph;
            #pragma unroll
            for (int hh = 0; hh < 4; ++hh) {
                float p0 = Pl[(jbase + 2 * hh) * 64 + i_loc];
                float p1 = Pl[(jbase + 2 * hh + 1) * 64 + i_loc];
                ph.u[hh] = cvtpk(p0, p1);
            }
            #pragma unroll
            for (int dt = 0; dt < 4; ++dt) {
                short8 af = *reinterpret_cast<const short8*>(
                    &KV[swz(dt * 32 + (lane & 31), jbase)]);
                oacc[dt] = __builtin_amdgcn_mfma_f32_32x32x16_bf16(af, ph.v, oacc[dt], 0, 0, 0);
            }
        }
    }
    __syncthreads();   // done reading Pl (P) and KV (V^T)

    // combine jt2 halves in LDS scratch osc[64][128] (Kh region, XOR-swizzled)
    float* osc = reinterpret_cast<float*>(Kh);
    if (jt2 == 1) {
        #pragma unroll
        for (int dt = 0; dt < 4; ++dt)
            #pragma unroll
            for (int r2 = 0; r2 < 16; ++r2) {
                int d = dt * 32 + (r2 & 3) + ((r2 >> 2) << 3) + (h5 << 2);
                osc[i_loc * 128 + (d ^ (i_loc & 28))] = oacc[dt][r2];
            }
    }
    __syncthreads();
    if (jt2 == 0) {
        #pragma unroll
        for (int dt = 0; dt < 4; ++dt)
            #pragma unroll
            for (int r2 = 0; r2 < 16; ++r2) {
                int d = dt * 32 + (r2 & 3) + ((r2 >> 2) << 3) + (h5 << 2);
                int a = i_loc * 128 + (d ^ (i_loc & 28));
                osc[a] += oacc[dt][r2];
            }
    }
    __syncthreads();

    // online-combined write: rnd 0 stores o_r; rnd>0: attn*a + o_r*b.
    #pragma unroll
    for (int w = 0; w < 8; ++w) {
        int lin = w * 256 + tid;          // float4 index over 64×32
        int rowq = lin >> 5;
        int d0 = (lin & 31) * 4;
        float4 sv4 = *reinterpret_cast<float4*>(&osc[rowq * 128 + (d0 ^ (rowq & 28))]);
        float* gp = attn + ((size_t)B * T_LEN + ktok[rowq]) * DH + d0;
        if (rnd == 0) {
            *reinterpret_cast<float4*>(gp) = sv4;
        } else {
            float aw = abrow[rowq][0], bw = abrow[rowq][1];
            float4 g = *reinterpret_cast<float4*>(gp);
            g.x = g.x * aw + sv4.x * bw;
            g.y = g.y * aw + sv4.y * bw;
            g.z = g.z * aw + sv4.z * bw;
            g.w = g.w * aw + sv4.w * bw;
            *reinterpret_cast<float4*>(gp) = g;
        }
    }
}

// ------------------------------------------------------------------
// K6: out = un-merge-heads(attn / S) @ w_out + b_out, 8 rows/block.
// ------------------------------------------------------------------
__global__ __launch_bounds__(256) void k_out(
    const float* __restrict__ attn, const float* __restrict__ Sbuf,
    const float* __restrict__ wout, const float* __restrict__ bout,
    float* __restrict__ out)
{
    __shared__ float as_[8][EMBD];     // 32 KB
    const int row0 = blockIdx.x * 8;
    const int tid = threadIdx.x;
    #pragma unroll
    for (int rr = 0; rr < 8; ++rr) {
        int row = row0 + rr;
        int b = row >> 12, t = row & 4095;
        for (int u = tid; u < EMBD; u += 256) {
            int h = u >> 7, d = u & 127;
            size_t gi = (size_t)(b * NHEADS + h) * T_LEN + t;
            as_[rr][u] = attn[gi * DH + d] / Sbuf[gi];
        }
    }
    __syncthreads();
    float acc[8][4] = {};
    const float* wp = wout + 4 * tid;
    for (int e = 0; e < EMBD; ++e) {
        float4 w4 = *reinterpret_cast<const float4*>(wp + (size_t)e * EMBD);
        #pragma unroll
        for (int rr = 0; rr < 8; ++rr) {
            float xe = as_[rr][e];
            acc[rr][0] = fmaf(xe, w4.x, acc[rr][0]);
            acc[rr][1] = fmaf(xe, w4.y, acc[rr][1]);
            acc[rr][2] = fmaf(xe, w4.z, acc[rr][2]);
            acc[rr][3] = fmaf(xe, w4.w, acc[rr][3]);
        }
    }
    int j = 4 * tid;
    float b0 = bout[j + 0], b1 = bout[j + 1], b2 = bout[j + 2], b3 = bout[j + 3];
    #pragma unroll
    for (int rr = 0; rr < 8; ++rr) {
        float4 o;
        o.x = acc[rr][0] + b0; o.y = acc[rr][1] + b1;
        o.z = acc[rr][2] + b2; o.w = acc[rr][3] + b3;
        *reinterpret_cast<float4*>(out + (size_t)(row0 + rr) * EMBD + j) = o;
    }
}

// ------------------------------------------------------------------
extern "C" void kernel_launch(void* const* d_in, const int* in_sizes, int n_in,
                              void* d_out, int out_size, void* d_ws, size_t ws_size,
                              hipStream_t stream)
{
    const float* x    = (const float*)d_in[0];
    const float* wqk  = (const float*)d_in[1];
    const float* wv   = (const float*)d_in[2];
    const float* wout = (const float*)d_in[3];
    const float* bout = (const float*)d_in[4];
    const float* rot  = (const float*)d_in[5];
    float* out = (float*)d_out;

    // ws layout (90.7 MB): qk32/qkr are PHASE-A-only, aliased by vb/attn.
    char* ws = (char*)d_ws;
    __hip_bfloat16* qkh       = (__hip_bfloat16*)(ws);
    __hip_bfloat16* qkl       = (__hip_bfloat16*)(ws + 16777216);
    float*          qk32      = (float*)        (ws + 33554432);
    __hip_bfloat16* qkr       = (__hip_bfloat16*)(ws + 67108864);
    __hip_bfloat16* vb        = (__hip_bfloat16*)(ws + 33554432);
    float*          attn      = (float*)        (ws + 50331648);
    unsigned*       bucketArr = (unsigned*)     (ws + 83886080);
    unsigned*       st        = (unsigned*)     (ws + 85983232);
    float*          Mbuf      = (float*)        (ws + 88080384);
    float*          Sbuf      = (float*)        (ws + 88342528);
    float*          rsn       = (float*)        (ws + 90439680);

    k_qk_gemm<<<2048, 512, 0, stream>>>(x, wqk, qk32, qkr, qkh, qkl, rsn);
    k_hash<<<1024, 256, 0, stream>>>(qk32, qkr, rot, bucketArr);
    // qk32/qkr dead from here; safe to write vb / attn (aliases)
    k_vproj<<<1024, 256, 0, stream>>>(x, wv, vb);
    k_sort<<<128, 64, 0, stream>>>(bucketArr, st);
    for (int r = 0; r < NHASH; ++r)
        k_bin_pv<<<1024, 256, 0, stream>>>(qkh, qkl, vb, rsn, st, Mbuf, Sbuf, attn, r);
    k_out<<<1024, 256, 0, stream>>>(attn, Sbuf, wout, bout, out);
}

// Round 18
// 1404.387 us; speedup vs baseline: 1.0693x; 1.0693x over previous
//
#include <hip/hip_runtime.h>
#include <hip/hip_bf16.h>
#include <math.h>

#define T_LEN 4096
#define EMBD 1024
#define DH 128
#define NHASH 8
#define NHEADS 8

typedef __attribute__((ext_vector_type(8))) short short8;
typedef __attribute__((ext_vector_type(16))) float f32x16;

// LDS swizzle: row-major [r][128] bf16, 16B-block XOR by (row&7) — G4 fix.
__device__ __forceinline__ int swz(int row, int col) {
    return (row << 7) + (col ^ ((row & 7) << 3));
}
__device__ __forceinline__ unsigned cvtpk(float lo, float hi) {
    unsigned r;
    asm("v_cvt_pk_bf16_f32 %0, %1, %2" : "=v"(r) : "v"(lo), "v"(hi));
    return r;
}
__device__ __forceinline__ float bfu_lo(unsigned u) {
    union { unsigned x; float f; } c; c.x = u << 16; return c.f;
}
__device__ __forceinline__ float bfu_hi(unsigned u) {
    union { unsigned x; float f; } c; c.x = u & 0xffff0000u; return c.f;
}
__device__ __forceinline__ float bfus2f(unsigned short s) {
    union { unsigned x; float f; } c; c.x = ((unsigned)s) << 16; return c.f;
}

// ------------------------------------------------------------------
// K1a: qk = x @ w_qk in f64, 16 rows/block (round-15 proven form).
// Emits qk32+qkr (2^-33), qkh/qkl (hi/lo bf16 of f32 qk), rsn.
// ------------------------------------------------------------------
__global__ __launch_bounds__(256) void k_qk_gemm(
    const float* __restrict__ x, const float* __restrict__ wqk,
    float* __restrict__ qk32, __hip_bfloat16* __restrict__ qkr,
    __hip_bfloat16* __restrict__ qkh, __hip_bfloat16* __restrict__ qkl,
    float* __restrict__ rsn)
{
    __shared__ float xs[16][EMBD];     // 64 KB
    const int row0 = blockIdx.x * 16;
    const int tid = threadIdx.x;

    #pragma unroll
    for (int rr = 0; rr < 16; ++rr)
        reinterpret_cast<float4*>(xs[rr])[tid] =
            reinterpret_cast<const float4*>(x + (size_t)(row0 + rr) * EMBD)[tid];
    __syncthreads();

    double a[16][4] = {};
    {
        const float* wp = wqk + 4 * tid;
        for (int e = 0; e < EMBD; ++e) {
            float4 w4 = *reinterpret_cast<const float4*>(wp + (size_t)e * EMBD);
            double w0 = (double)w4.x, w1 = (double)w4.y;
            double w2 = (double)w4.z, w3 = (double)w4.w;
            #pragma unroll
            for (int rr = 0; rr < 16; ++rr) {
                double xe = (double)xs[rr][e];
                a[rr][0] = fma(xe, w0, a[rr][0]);
                a[rr][1] = fma(xe, w1, a[rr][1]);
                a[rr][2] = fma(xe, w2, a[rr][2]);
                a[rr][3] = fma(xe, w3, a[rr][3]);
            }
        }
    }
    const int j = 4 * tid;
    const int h = j >> 7, d = j & 127;
    #pragma unroll
    for (int rr = 0; rr < 16; ++rr) {
        float f0 = (float)a[rr][0], f1 = (float)a[rr][1];
        float f2 = (float)a[rr][2], f3 = (float)a[rr][3];
        float ss = f0*f0 + f1*f1 + f2*f2 + f3*f3;
        #pragma unroll
        for (int m = 1; m < 32; m <<= 1) ss += __shfl_xor(ss, m);
        float rs = 1.0f / sqrtf(fmaxf(ss, 1e-12f));

        int row = row0 + rr;
        int b = row >> 12, t = row & 4095;
        size_t base = ((size_t)(b * NHEADS + h) * T_LEN + t) * DH + d;

        float4 q4; q4.x = f0; q4.y = f1; q4.z = f2; q4.w = f3;
        *reinterpret_cast<float4*>(qk32 + base) = q4;
        float r0 = (float)(a[rr][0] - (double)f0);
        float r1 = (float)(a[rr][1] - (double)f1);
        float r2 = (float)(a[rr][2] - (double)f2);
        float r3 = (float)(a[rr][3] - (double)f3);
        *reinterpret_cast<uint2*>(qkr + base) = make_uint2(cvtpk(r0, r1), cvtpk(r2, r3));

        unsigned h01 = cvtpk(f0, f1), h23 = cvtpk(f2, f3);
        float l0 = f0 - bfu_lo(h01), l1 = f1 - bfu_hi(h01);
        float l2 = f2 - bfu_lo(h23), l3 = f3 - bfu_hi(h23);
        *reinterpret_cast<uint2*>(qkh + base) = make_uint2(h01, h23);
        *reinterpret_cast<uint2*>(qkl + base) = make_uint2(cvtpk(l0, l1), cvtpk(l2, l3));
        if ((tid & 31) == 0)
            rsn[(size_t)(b * NHEADS + h) * T_LEN + t] = rs;
    }
}

// ------------------------------------------------------------------
// K1b: LSH hash — unchanged (proven).
// ------------------------------------------------------------------
__global__ __launch_bounds__(256) void k_hash(
    const float* __restrict__ qk32, const __hip_bfloat16* __restrict__ qkr,
    const float* __restrict__ rot, unsigned* __restrict__ bucketArr)
{
    __shared__ double qs[8][EMBD];     // 64 KB
    const int tok0 = blockIdx.x * 8;
    const int tid = threadIdx.x;
    const int j = 4 * tid;
    const int h = j >> 7, d = j & 127;

    #pragma unroll
    for (int tk = 0; tk < 8; ++tk) {
        int row = tok0 + tk;
        int b = row >> 12, t = row & 4095;
        size_t base = ((size_t)(b * NHEADS + h) * T_LEN + t) * DH + d;
        float4 f4 = *reinterpret_cast<const float4*>(qk32 + base);
        ushort4 r4 = *reinterpret_cast<const ushort4*>(qkr + base);
        qs[tk][j + 0] = (double)f4.x + (double)bfus2f(r4.x);
        qs[tk][j + 1] = (double)f4.y + (double)bfus2f(r4.y);
        qs[tk][j + 2] = (double)f4.z + (double)bfus2f(r4.z);
        qs[tk][j + 3] = (double)f4.w + (double)bfus2f(r4.w);
    }
    __syncthreads();

    const int r = tid >> 5, i = tid & 31;
    const float* rp = rot + r * 32 + i;
    for (int hh = 0; hh < NHEADS; ++hh) {
        double acc[8] = {};
        for (int f = 0; f < DH; ++f) {
            double rv = (double)rp[(size_t)f * 256];
            #pragma unroll
            for (int tk = 0; tk < 8; ++tk)
                acc[tk] = fma(qs[tk][hh * DH + f], rv, acc[tk]);
        }
        #pragma unroll
        for (int tk = 0; tk < 8; ++tk) {
            double v; int idx;
            if (acc[tk] >= 0.0) { v = acc[tk]; idx = i; } else { v = -acc[tk]; idx = i + 32; }
            #pragma unroll
            for (int m = 1; m < 32; m <<= 1) {
                double ov = __shfl_xor(v, m);
                int oi = __shfl_xor(idx, m);
                if (ov > v || (ov == v && oi < idx)) { v = ov; idx = oi; }
            }
            if (i == 0) {
                int row = tok0 + tk;
                int b = row >> 12, t = row & 4095;
                bucketArr[((size_t)(b * NHEADS + hh) * NHASH + r) * T_LEN + t] = (unsigned)idx;
            }
        }
    }
}

// ------------------------------------------------------------------
// K2: v = x @ w_v, 8 rows/block -> v_bf16 (proven).
// ------------------------------------------------------------------
__global__ __launch_bounds__(256) void k_vproj(
    const float* __restrict__ x, const float* __restrict__ wv,
    __hip_bfloat16* __restrict__ vb)
{
    __shared__ float xs[8][EMBD];      // 32 KB
    const int row0 = blockIdx.x * 8;
    const int tid = threadIdx.x;
    #pragma unroll
    for (int rr = 0; rr < 8; ++rr)
        reinterpret_cast<float4*>(xs[rr])[tid] =
            reinterpret_cast<const float4*>(x + (size_t)(row0 + rr) * EMBD)[tid];
    __syncthreads();

    float acc[8][4] = {};
    const float* wp = wv + 4 * tid;
    for (int e = 0; e < EMBD; ++e) {
        float4 w4 = *reinterpret_cast<const float4*>(wp + (size_t)e * EMBD);
        #pragma unroll
        for (int rr = 0; rr < 8; ++rr) {
            float xe = xs[rr][e];
            acc[rr][0] = fmaf(xe, w4.x, acc[rr][0]);
            acc[rr][1] = fmaf(xe, w4.y, acc[rr][1]);
            acc[rr][2] = fmaf(xe, w4.z, acc[rr][2]);
            acc[rr][3] = fmaf(xe, w4.w, acc[rr][3]);
        }
    }
    int j = 4 * tid;
    int h = j >> 7, d = j & 127;
    #pragma unroll
    for (int rr = 0; rr < 8; ++rr) {
        int row = row0 + rr;
        int b = row >> 12, t = row & 4095;
        *reinterpret_cast<uint2*>(vb + ((size_t)(b * NHEADS + h) * T_LEN + t) * DH + d)
            = make_uint2(cvtpk(acc[rr][0], acc[rr][1]), cvtpk(acc[rr][2], acc[rr][3]));
    }
}

// ------------------------------------------------------------------
// K3: stable counting sort per (B, hash-round) — unchanged (proven).
// ------------------------------------------------------------------
__global__ __launch_bounds__(64) void k_sort(
    const unsigned* __restrict__ bucketArr, unsigned* __restrict__ st)
{
    __shared__ unsigned short bkt[T_LEN];
    __shared__ unsigned hist[64][64];
    __shared__ unsigned bstart[64];
    const int B = blockIdx.x >> 3, r = blockIdx.x & 7;
    const unsigned* src = bucketArr + ((size_t)B * NHASH + r) * T_LEN;
    const int tid = threadIdx.x;

    for (int k = tid; k < T_LEN; k += 64) bkt[k] = (unsigned short)src[k];
    for (int k = tid; k < 64 * 64; k += 64) (&hist[0][0])[k] = 0;
    __syncthreads();
    {
        const int base = tid * 64;
        for (int k = 0; k < 64; ++k) hist[tid][bkt[base + k]]++;
    }
    __syncthreads();
    {
        unsigned tot = 0;
        for (int c = 0; c < 64; ++c) tot += hist[c][tid];
        bstart[tid] = tot;
    }
    __syncthreads();
    if (tid == 0) {
        unsigned run = 0;
        for (int q = 0; q < 64; ++q) { unsigned c = bstart[q]; bstart[q] = run; run += c; }
    }
    __syncthreads();
    {
        unsigned run = bstart[tid];
        for (int c = 0; c < 64; ++c) { unsigned h = hist[c][tid]; hist[c][tid] = run; run += h; }
    }
    __syncthreads();
    {
        unsigned* dst = st + ((size_t)B * NHASH + r) * T_LEN;
        const int base = tid * 64;
        for (int k = 0; k < 64; ++k) {
            unsigned bb2 = bkt[base + k];
            unsigned p = hist[tid][bb2]++;
            dst[p] = (unsigned)(base + k);
        }
    }
}

// ------------------------------------------------------------------
// K4: per-bin attention, ONE PASS per hash round (online cross-round
// softmax). LDS ~52 KB (3 blocks/CU): P as bf16 pairs in Pb (16 KB,
// BOTH packs per quadruple — round-17 bug fixed); Kh time-shared
// K_hi -> V^T -> osc. Math bit-identical to round 16.
// ------------------------------------------------------------------
__global__ __launch_bounds__(256, 3) void k_bin_pv(
    const __hip_bfloat16* __restrict__ qkh, const __hip_bfloat16* __restrict__ qkl,
    const __hip_bfloat16* __restrict__ vb, const float* __restrict__ rsn,
    const unsigned* __restrict__ st, float* __restrict__ Mbuf,
    float* __restrict__ Sbuf, float* __restrict__ attn, int rnd)
{
    __shared__ short Kh[128 * 128];        // K_hi -> V^T -> osc f32[64][128]
    __shared__ unsigned short Pb[64 * 128];// P bf16: [(j>>1)][i][j&1], 16 KB
    __shared__ int ktok[128];
    __shared__ float rs_l[128];
    __shared__ float red4b[2][2][2][32];   // [it][jt2][h5][col]
    __shared__ float mrow[64];
    __shared__ float abrow[64][2];         // per-query (a, b) weights

    const int tid = threadIdx.x;
    const int c = blockIdx.x & 63;
    const int B = blockIdx.x >> 6;
    const unsigned* stp = st + ((size_t)B * NHASH + rnd) * T_LEN;

    if (tid < 128) {
        int cc = (tid < 64) ? c : (c == 0 ? 1 : c - 1);
        int tok = (int)stp[cc * 64 + (tid & 63)];
        ktok[tid] = tok;
        rs_l[tid] = rsn[(size_t)B * T_LEN + tok];
    }
    __syncthreads();

    // stage K_hi (swizzled)
    for (int u = tid; u < 128 * 16; u += 256) {
        int row = u >> 4, blk = u & 15;
        *reinterpret_cast<int4*>(&Kh[swz(row, blk * 8)]) =
            *reinterpret_cast<const int4*>(qkh + ((size_t)B * T_LEN + ktok[row]) * DH + blk * 8);
    }

    const int wave = tid >> 6, lane = tid & 63;
    const int it = wave & 1, jt2 = wave >> 1;
    const int h5 = lane >> 5;
    const int i_loc = it * 32 + (lane & 31);
    const int qtok_i = ktok[i_loc];
    short8 qfh[8], qfl[8];
    {
        size_t qoff = ((size_t)B * T_LEN + qtok_i) * DH + (h5 << 3);
        #pragma unroll
        for (int kt = 0; kt < 8; ++kt) {
            qfh[kt] = *reinterpret_cast<const short8*>(qkh + qoff + kt * 16);
            qfl[kt] = *reinterpret_cast<const short8*>(qkl + qoff + kt * 16);
        }
    }
    __syncthreads();

    const float scale = 0.08838834764831845f;
    float p2[2][16];   // raw masked dots, then P
    #pragma unroll
    for (int jj = 0; jj < 2; ++jj) {
        int jt = jt2 * 2 + jj;
        f32x16 acc = {};
        #pragma unroll
        for (int kt = 0; kt < 8; ++kt) {        // FULL K, 2-term split S
            int so = swz(jt * 32 + (lane & 31), kt * 16 + (h5 << 3));
            short8 afh = *reinterpret_cast<const short8*>(&Kh[so]);
            acc = __builtin_amdgcn_mfma_f32_32x32x16_bf16(afh, qfh[kt], acc, 0, 0, 0);
            acc = __builtin_amdgcn_mfma_f32_32x32x16_bf16(afh, qfl[kt], acc, 0, 0, 0);
        }
        #pragma unroll
        for (int r2 = 0; r2 < 16; ++r2) {
            int jl = (r2 & 3) + ((r2 >> 2) << 3) + (h5 << 2);
            int jf = jt * 32 + jl;
            float s = acc[r2] * (scale * rs_l[jf]);
            p2[jj][r2] = (ktok[jf] == qtok_i) ? -1e5f : s;
        }
    }

    // ---- per-query max over 128 keys ----
    float mloc = p2[0][0];
    #pragma unroll
    for (int jj = 0; jj < 2; ++jj)
        #pragma unroll
        for (int r2 = 0; r2 < 16; ++r2) mloc = fmaxf(mloc, p2[jj][r2]);
    red4b[it][jt2][h5][lane & 31] = mloc;
    __syncthreads();                       // also: all Kh dot-reads done
    if (tid < 64) {
        int it2 = tid >> 5, i = tid & 31;
        mrow[tid] = fmaxf(fmaxf(red4b[it2][0][0][i], red4b[it2][0][1][i]),
                          fmaxf(red4b[it2][1][0][i], red4b[it2][1][1][i]));
    }
    __syncthreads();

    // ---- P = exp(S - m); per-query sum ----
    const float mi = mrow[i_loc];
    float sloc = 0.f;
    #pragma unroll
    for (int jj = 0; jj < 2; ++jj)
        #pragma unroll
        for (int r2 = 0; r2 < 16; ++r2) {
            float p = __expf(p2[jj][r2] - mi);
            p2[jj][r2] = p;
            sloc += p;
        }
    red4b[it][jt2][h5][lane & 31] = sloc;
    __syncthreads();

    // ---- s-merge + global M/S update; write Pb; stage V^T into Kh ----
    if (tid < 64) {
        int it2 = tid >> 5, i = tid & 31;
        float sr = red4b[it2][0][0][i] + red4b[it2][0][1][i] +
                   red4b[it2][1][0][i] + red4b[it2][1][1][i];
        float m = mrow[tid];
        size_t gi = (size_t)B * T_LEN + ktok[tid];
        float aw, bw;
        if (rnd == 0) {
            Mbuf[gi] = m; Sbuf[gi] = sr;
            aw = 0.f; bw = 1.f;
        } else {
            float Mold = Mbuf[gi];
            float Mnew = fmaxf(Mold, m);
            aw = __expf(Mold - Mnew);
            bw = __expf(m - Mnew);
            Sbuf[gi] = Sbuf[gi] * aw + sr * bw;
            Mbuf[gi] = Mnew;
        }
        abrow[tid][0] = aw; abrow[tid][1] = bw;
    }
    // P -> bf16 pairs: quadruple q covers rows 8q+4h5+{0..3} at col i_loc
    //   pack0 (rows +0,+1) at jhalf; pack1 (rows +2,+3) at jhalf+1.
    #pragma unroll
    for (int jj = 0; jj < 2; ++jj) {
        int jt = jt2 * 2 + jj;
        #pragma unroll
        for (int q = 0; q < 4; ++q) {
            int jhalf = jt * 16 + 4 * q + 2 * h5;   // (row>>1), row even
            unsigned pk0 = cvtpk(p2[jj][4 * q + 0], p2[jj][4 * q + 1]);
            unsigned pk1 = cvtpk(p2[jj][4 * q + 2], p2[jj][4 * q + 3]);
            *reinterpret_cast<unsigned*>(&Pb[jhalf * 128 + i_loc * 2]) = pk0;
            *reinterpret_cast<unsigned*>(&Pb[(jhalf + 1) * 128 + i_loc * 2]) = pk1;
        }
    }
    // restage Kh region as V^T (swizzled rows of V^T: row=d, col=j)
    {
        int j2 = tid >> 1, dbase = (tid & 1) * 64;
        const __hip_bfloat16* vrow = vb + ((size_t)B * T_LEN + ktok[j2]) * DH + dbase;
        #pragma unroll
        for (int mch = 0; mch < 8; ++mch) {
            short8 vv = *reinterpret_cast<const short8*>(vrow + mch * 8);
            #pragma unroll
            for (int e = 0; e < 8; ++e)
                Kh[swz(dbase + mch * 8 + e, j2)] = vv[e];
        }
    }
    __syncthreads();

    // MFMA PV: B-frags read directly from Pb (4 u32 each); A = V^T tiles.
    f32x16 oacc[4] = {};
    #pragma unroll
    for (int jj = 0; jj < 2; ++jj) {
        int jt = jt2 * 2 + jj;
        #pragma unroll
        for (int ks = 0; ks < 2; ++ks) {
            int jb0 = jt * 32 + ks * 16 + h5 * 8;   // even
            union Pack { unsigned u[4]; short8 v; } ph;
            #pragma unroll
            for (int m = 0; m < 4; ++m)
                ph.u[m] = *reinterpret_cast<const unsigned*>(
                    &Pb[((jb0 >> 1) + m) * 128 + i_loc * 2]);
            #pragma unroll
            for (int dt = 0; dt < 4; ++dt) {
                short8 af = *reinterpret_cast<const short8*>(
                    &Kh[swz(dt * 32 + (lane & 31), jb0)]);
                oacc[dt] = __builtin_amdgcn_mfma_f32_32x32x16_bf16(af, ph.v, oacc[dt], 0, 0, 0);
            }
        }
    }
    __syncthreads();   // done reading Pb and V^T(Kh)

    // combine jt2 halves in osc[64][128] f32 (Kh region, XOR-swizzled)
    float* osc = reinterpret_cast<float*>(Kh);
    if (jt2 == 1) {
        #pragma unroll
        for (int dt = 0; dt < 4; ++dt)
            #pragma unroll
            for (int r2 = 0; r2 < 16; ++r2) {
                int d = dt * 32 + (r2 & 3) + ((r2 >> 2) << 3) + (h5 << 2);
                osc[i_loc * 128 + (d ^ (i_loc & 28))] = oacc[dt][r2];
            }
    }
    __syncthreads();
    if (jt2 == 0) {
        #pragma unroll
        for (int dt = 0; dt < 4; ++dt)
            #pragma unroll
            for (int r2 = 0; r2 < 16; ++r2) {
                int d = dt * 32 + (r2 & 3) + ((r2 >> 2) << 3) + (h5 << 2);
                int a = i_loc * 128 + (d ^ (i_loc & 28));
                osc[a] += oacc[dt][r2];
            }
    }
    __syncthreads();

    // online-combined write: rnd 0 stores o_r; rnd>0: attn*a + o_r*b.
    #pragma unroll
    for (int w = 0; w < 8; ++w) {
        int lin = w * 256 + tid;          // float4 index over 64×32
        int rowq = lin >> 5;
        int d0 = (lin & 31) * 4;
        float4 sv4 = *reinterpret_cast<float4*>(&osc[rowq * 128 + (d0 ^ (rowq & 28))]);
        float* gp = attn + ((size_t)B * T_LEN + ktok[rowq]) * DH + d0;
        if (rnd == 0) {
            *reinterpret_cast<float4*>(gp) = sv4;
        } else {
            float aw = abrow[rowq][0], bw = abrow[rowq][1];
            float4 g = *reinterpret_cast<float4*>(gp);
            g.x = g.x * aw + sv4.x * bw;
            g.y = g.y * aw + sv4.y * bw;
            g.z = g.z * aw + sv4.z * bw;
            g.w = g.w * aw + sv4.w * bw;
            *reinterpret_cast<float4*>(gp) = g;
        }
    }
}

// ------------------------------------------------------------------
// K6: out = un-merge-heads(attn / S) @ w_out + b_out, 8 rows/block.
// ------------------------------------------------------------------
__global__ __launch_bounds__(256) void k_out(
    const float* __restrict__ attn, const float* __restrict__ Sbuf,
    const float* __restrict__ wout, const float* __restrict__ bout,
    float* __restrict__ out)
{
    __shared__ float as_[8][EMBD];     // 32 KB
    const int row0 = blockIdx.x * 8;
    const int tid = threadIdx.x;
    #pragma unroll
    for (int rr = 0; rr < 8; ++rr) {
        int row = row0 + rr;
        int b = row >> 12, t = row & 4095;
        for (int u = tid; u < EMBD; u += 256) {
            int h = u >> 7, d = u & 127;
            size_t gi = (size_t)(b * NHEADS + h) * T_LEN + t;
            as_[rr][u] = attn[gi * DH + d] / Sbuf[gi];
        }
    }
    __syncthreads();
    float acc[8][4] = {};
    const float* wp = wout + 4 * tid;
    for (int e = 0; e < EMBD; ++e) {
        float4 w4 = *reinterpret_cast<const float4*>(wp + (size_t)e * EMBD);
        #pragma unroll
        for (int rr = 0; rr < 8; ++rr) {
            float xe = as_[rr][e];
            acc[rr][0] = fmaf(xe, w4.x, acc[rr][0]);
            acc[rr][1] = fmaf(xe, w4.y, acc[rr][1]);
            acc[rr][2] = fmaf(xe, w4.z, acc[rr][2]);
            acc[rr][3] = fmaf(xe, w4.w, acc[rr][3]);
        }
    }
    int j = 4 * tid;
    float b0 = bout[j + 0], b1 = bout[j + 1], b2 = bout[j + 2], b3 = bout[j + 3];
    #pragma unroll
    for (int rr = 0; rr < 8; ++rr) {
        float4 o;
        o.x = acc[rr][0] + b0; o.y = acc[rr][1] + b1;
        o.z = acc[rr][2] + b2; o.w = acc[rr][3] + b3;
        *reinterpret_cast<float4*>(out + (size_t)(row0 + rr) * EMBD + j) = o;
    }
}

// ------------------------------------------------------------------
extern "C" void kernel_launch(void* const* d_in, const int* in_sizes, int n_in,
                              void* d_out, int out_size, void* d_ws, size_t ws_size,
                              hipStream_t stream)
{
    const float* x    = (const float*)d_in[0];
    const float* wqk  = (const float*)d_in[1];
    const float* wv   = (const float*)d_in[2];
    const float* wout = (const float*)d_in[3];
    const float* bout = (const float*)d_in[4];
    const float* rot  = (const float*)d_in[5];
    float* out = (float*)d_out;

    // ws layout (90.7 MB): qk32/qkr are PHASE-A-only, aliased by vb/attn.
    char* ws = (char*)d_ws;
    __hip_bfloat16* qkh       = (__hip_bfloat16*)(ws);
    __hip_bfloat16* qkl       = (__hip_bfloat16*)(ws + 16777216);
    float*          qk32      = (float*)        (ws + 33554432);
    __hip_bfloat16* qkr       = (__hip_bfloat16*)(ws + 67108864);
    __hip_bfloat16* vb        = (__hip_bfloat16*)(ws + 33554432);
    float*          attn      = (float*)        (ws + 50331648);
    unsigned*       bucketArr = (unsigned*)     (ws + 83886080);
    unsigned*       st        = (unsigned*)     (ws + 85983232);
    float*          Mbuf      = (float*)        (ws + 88080384);
    float*          Sbuf      = (float*)        (ws + 88342528);
    float*          rsn       = (float*)        (ws + 90439680);

    k_qk_gemm<<<512, 256, 0, stream>>>(x, wqk, qk32, qkr, qkh, qkl, rsn);
    k_hash<<<1024, 256, 0, stream>>>(qk32, qkr, rot, bucketArr);
    // qk32/qkr dead from here; safe to write vb / attn (aliases)
    k_vproj<<<1024, 256, 0, stream>>>(x, wv, vb);
    k_sort<<<128, 64, 0, stream>>>(bucketArr, st);
    for (int r = 0; r < NHASH; ++r)
        k_bin_pv<<<1024, 256, 0, stream>>>(qkh, qkl, vb, rsn, st, Mbuf, Sbuf, attn, r);
    k_out<<<1024, 256, 0, stream>>>(attn, Sbuf, wout, bout, out);
}